// Round 5
// baseline (151.397 us; speedup 1.0000x reference)
//
#include <hip/hip_runtime.h>

#define N 8000
#define SEQ 200
#define MAX_STEPS 199

#define NBLOCKS 2048                    // block 0 = loss, 1..2047 = regularizer
#define NTHREADS 256
#define REG_T (2047 * NTHREADS)         // 524,032 reg threads
#define NN4 16000000                    // N*N/4 float4 per matrix
// 30 full strides: 30*524,032 = 15,720,960; tail stride 30 covers 279,040
#define FULL_STRIDES 30

typedef float f4 __attribute__((ext_vector_type(4)));

__device__ __forceinline__ float log_sum4(f4 v) {
    // log(|x|+1) = ln2 * log2(|x|+1); ln2*0.5 folded into the final atomic.
    return __log2f(fabsf(v[0]) + 1.0f) + __log2f(fabsf(v[1]) + 1.0f) +
           __log2f(fabsf(v[2]) + 1.0f) + __log2f(fabsf(v[3]) + 1.0f);
}

__global__ void __launch_bounds__(NTHREADS)
k_fused(const int* __restrict__ a,
        const float* __restrict__ s,
        const float* __restrict__ pe,
        const float* __restrict__ ne,
        const float* __restrict__ kp,
        float* __restrict__ out) {
    __shared__ float wsum[NTHREADS / 64];
    const int tid = threadIdx.x;

    if (blockIdx.x == 0) {
        // ------------------- sequential loss (1 block, hidden under reg) ----
        __shared__ int   sa[MAX_STEPS];
        __shared__ float ss[MAX_STEPS];
        for (int i = tid; i < MAX_STEPS; i += NTHREADS) {
            sa[i] = a[i];
            ss[i] = s[i];
        }
        __syncthreads();

        __shared__ int V;
        if (tid == 0) {
            int v = MAX_STEPS;
            for (int t = 0; t < MAX_STEPS; ++t)
                if (ss[t] < 0.0f) { v = t; break; }
            V = v;
        }
        __syncthreads();

        float li = 0.0f;
        if (tid < MAX_STEPS && tid < V) {
            const int j = sa[tid];
            float k = kp[j];
            int t = 0;
            // batched-8 prefetch: loads are independent of the fold chain
            for (; t + 8 <= tid; t += 8) {
                float pv[8], nv[8];
                #pragma unroll
                for (int u = 0; u < 8; ++u) {
                    size_t off = (size_t)sa[t + u] * N + (size_t)j;
                    pv[u] = pe[off];
                    nv[u] = ne[off];
                }
                #pragma unroll
                for (int u = 0; u < 8; ++u) {
                    float st = ss[t + u];
                    float d = st * pv[u] + (1.0f - st) * nv[u];
                    k = fminf(fmaxf(k + d, -30.0f), 30.0f);
                }
            }
            for (; t < tid; ++t) {
                float st = ss[t];
                size_t off = (size_t)sa[t] * N + (size_t)j;
                float d = st * pe[off] + (1.0f - st) * ne[off];
                k = fminf(fmaxf(k + d, -30.0f), 30.0f);
            }
            float p = fminf(fmaxf(k, 0.01f), 0.99f);
            li = -(ss[tid] * logf(p) + (1.0f - ss[tid]) * logf(1.0f - p));
        }

        #pragma unroll
        for (int o = 32; o > 0; o >>= 1) li += __shfl_down(li, o);
        if ((tid & 63) == 0) wsum[tid >> 6] = li;
        __syncthreads();
        if (tid == 0) {
            float total = 0.0f;
            #pragma unroll
            for (int w = 0; w < NTHREADS / 64; ++w) total += wsum[w];
            atomicAdd(out, total);
        }
        return;
    }

    // --------------- regularizer (2047 blocks, R2-exact loop body) ----------
    const f4* __restrict__ pe4 = (const f4*)pe;
    const f4* __restrict__ ne4 = (const f4*)ne;
    const int rt = (int)(blockIdx.x - 1) * NTHREADS + tid;   // 0 .. REG_T-1

    float acc = 0.0f;
    // 2-deep interleaved streams, unroll 2 -> 4 loads in flight per iter
    #pragma unroll 2
    for (int k = 0; k < FULL_STRIDES; ++k) {
        size_t p = (size_t)rt + (size_t)k * REG_T;
        f4 v = pe4[p];
        f4 w = ne4[p];
        acc += log_sum4(v);
        acc += log_sum4(w);
    }
    // stride 30 (partial: rt < 279,040)
    {
        size_t p = (size_t)rt + (size_t)FULL_STRIDES * REG_T;
        if (p < (size_t)NN4) {
            f4 v = pe4[p];
            f4 w = ne4[p];
            acc += log_sum4(v);
            acc += log_sum4(w);
        }
    }

    // wave64 reduce + block reduce
    #pragma unroll
    for (int o = 32; o > 0; o >>= 1) acc += __shfl_down(acc, o);
    if ((tid & 63) == 0) wsum[tid >> 6] = acc;
    __syncthreads();
    if (tid == 0) {
        float b = 0.0f;
        #pragma unroll
        for (int w = 0; w < NTHREADS / 64; ++w) b += wsum[w];
        // 0.5 * ln(2): log2 -> ln conversion + the 0.5 regularizer factor
        atomicAdd(out, 0.34657359027997264f * b);
    }
}

extern "C" void kernel_launch(void* const* d_in, const int* in_sizes, int n_in,
                              void* d_out, int out_size, void* d_ws, size_t ws_size,
                              hipStream_t stream) {
    const int*   a  = (const int*)d_in[0];
    const float* s  = (const float*)d_in[1];
    const float* pe = (const float*)d_in[2];
    const float* ne = (const float*)d_in[3];
    const float* kp = (const float*)d_in[4];
    float* out = (float*)d_out;

    hipMemsetAsync(out, 0, sizeof(float), stream);
    k_fused<<<NBLOCKS, NTHREADS, 0, stream>>>(a, s, pe, ne, kp, out);
}

// Round 6
// 112.349 us; speedup vs baseline: 1.3476x; 1.3476x over previous
//
#include <hip/hip_runtime.h>

#define N 8000
#define SEQ 200
#define MAX_STEPS 199

#define REG_BLOCKS 2048
#define REG_THREADS 256
#define REG_TOTAL (REG_BLOCKS * REG_THREADS)          // 524288
#define NN4 16000000                                  // N*N/4 float4 per matrix
#define NFULL 30                                      // 30*524288 = 15,728,640

typedef float f4 __attribute__((ext_vector_type(4)));

__device__ __forceinline__ float log_sum4(f4 v) {
    // log(|x|+1) = ln2 * log2(|x|+1); ln2*0.5 folded into the final atomic.
    return __log2f(fabsf(v[0]) + 1.0f) + __log2f(fabsf(v[1]) + 1.0f) +
           __log2f(fabsf(v[2]) + 1.0f) + __log2f(fabsf(v[3]) + 1.0f);
}

// -------------------------------------------------------------------------
// K1: zero out; gather D[t][i] = s_t*pe[a_t][a_i] + (1-s_t)*ne[a_t][a_i]
//     into workspace. 39601 threads over 155 blocks -> scatter is parallel.
// -------------------------------------------------------------------------
__global__ void k_init_gather(const int* __restrict__ a,
                              const float* __restrict__ s,
                              const float* __restrict__ pe,
                              const float* __restrict__ ne,
                              float* __restrict__ D, int useD,
                              float* __restrict__ out) {
    if (blockIdx.x == 0 && threadIdx.x == 0) out[0] = 0.0f;
    if (!useD) return;

    __shared__ int   sa[MAX_STEPS];
    __shared__ float ss[MAX_STEPS];
    for (int i = threadIdx.x; i < MAX_STEPS; i += blockDim.x) {
        sa[i] = a[i];
        ss[i] = s[i];
    }
    __syncthreads();

    int idx = blockIdx.x * blockDim.x + threadIdx.x;
    const int total = MAX_STEPS * MAX_STEPS;
    if (idx < total) {
        int t = idx / MAX_STEPS;
        int i = idx - t * MAX_STEPS;
        float st = ss[t];
        size_t off = (size_t)sa[t] * N + (size_t)sa[i];
        float d = st * pe[off] + (1.0f - st) * ne[off];
        D[idx] = d;
    }
}

// -------------------------------------------------------------------------
// K2: regularizer. R2-exact body EXCEPT loads are non-temporal on BOTH
//     matrices: no LLC allocation -> steady-state reads are a pure HBM
//     stream instead of a 50% L3-thrash mix.
// -------------------------------------------------------------------------
__global__ void __launch_bounds__(REG_THREADS)
k_reg(const float* __restrict__ pe,
      const float* __restrict__ ne,
      float* __restrict__ out) {
    const f4* __restrict__ pe4 = (const f4*)pe;
    const f4* __restrict__ ne4 = (const f4*)ne;
    const int tid0 = blockIdx.x * REG_THREADS + threadIdx.x;

    float acc = 0.0f;
    #pragma unroll 2
    for (int k = 0; k < NFULL; ++k) {
        size_t p = (size_t)tid0 + (size_t)k * REG_TOTAL;
        f4 v = __builtin_nontemporal_load(&pe4[p]);
        f4 w = __builtin_nontemporal_load(&ne4[p]);
        acc += log_sum4(v);
        acc += log_sum4(w);
    }
    // guarded tail stride
    {
        size_t p = (size_t)tid0 + (size_t)NFULL * REG_TOTAL;
        if (p < (size_t)NN4) {
            f4 v = __builtin_nontemporal_load(&pe4[p]);
            f4 w = __builtin_nontemporal_load(&ne4[p]);
            acc += log_sum4(v);
            acc += log_sum4(w);
        }
    }

    // wave64 reduce
    #pragma unroll
    for (int o = 32; o > 0; o >>= 1) acc += __shfl_down(acc, o);
    __shared__ float wsum[REG_THREADS / 64];
    int lane = threadIdx.x & 63;
    int wid  = threadIdx.x >> 6;
    if (lane == 0) wsum[wid] = acc;
    __syncthreads();
    if (threadIdx.x == 0) {
        float b = 0.0f;
        #pragma unroll
        for (int w = 0; w < REG_THREADS / 64; ++w) b += wsum[w];
        // 0.5 * ln(2) folded here (log2 -> ln conversion)
        atomicAdd(out, 0.34657359027997264f * b);
    }
}

// -------------------------------------------------------------------------
// K3: sequential loss from D (coalesced columns, L2-resident). 1 block.
// -------------------------------------------------------------------------
__global__ void k_loss(const int* __restrict__ a,
                       const float* __restrict__ s,
                       const float* __restrict__ pe,
                       const float* __restrict__ ne,
                       const float* __restrict__ kp,
                       const float* __restrict__ D, int useD,
                       float* __restrict__ out) {
    __shared__ int   sa[MAX_STEPS];
    __shared__ float ss[MAX_STEPS];
    int tid = threadIdx.x;
    for (int i = tid; i < MAX_STEPS; i += blockDim.x) {
        sa[i] = a[i];
        ss[i] = s[i];
    }
    __syncthreads();

    __shared__ int V;
    if (tid == 0) {
        int v = MAX_STEPS;
        for (int t = 0; t < MAX_STEPS; ++t) {
            if (ss[t] < 0.0f) { v = t; break; }
        }
        V = v;
    }
    __syncthreads();

    float li = 0.0f;
    if (tid < MAX_STEPS && tid < V) {
        int j = sa[tid];
        float k = kp[j];
        if (useD) {
            int t = 0;
            for (; t + 8 <= tid; t += 8) {
                float d[8];
                #pragma unroll
                for (int u = 0; u < 8; ++u) d[u] = D[(t + u) * MAX_STEPS + tid];
                #pragma unroll
                for (int u = 0; u < 8; ++u)
                    k = fminf(fmaxf(k + d[u], -30.0f), 30.0f);
            }
            for (; t < tid; ++t) {
                float d = D[t * MAX_STEPS + tid];
                k = fminf(fmaxf(k + d, -30.0f), 30.0f);
            }
        } else {
            for (int t = 0; t < tid; ++t) {
                float st = ss[t];
                size_t off = (size_t)sa[t] * N + (size_t)j;
                float d = st * pe[off] + (1.0f - st) * ne[off];
                k = fminf(fmaxf(k + d, -30.0f), 30.0f);
            }
        }
        float p = fminf(fmaxf(k, 0.01f), 0.99f);
        li = -(ss[tid] * logf(p) + (1.0f - ss[tid]) * logf(1.0f - p));
    }

    #pragma unroll
    for (int o = 32; o > 0; o >>= 1) li += __shfl_down(li, o);
    __shared__ float wsum[4];
    int lane = tid & 63;
    int wid  = tid >> 6;
    if (lane == 0) wsum[wid] = li;
    __syncthreads();
    if (tid == 0) {
        float total = wsum[0] + wsum[1] + wsum[2] + wsum[3];
        atomicAdd(out, total);
    }
}

extern "C" void kernel_launch(void* const* d_in, const int* in_sizes, int n_in,
                              void* d_out, int out_size, void* d_ws, size_t ws_size,
                              hipStream_t stream) {
    const int*   a  = (const int*)d_in[0];
    const float* s  = (const float*)d_in[1];
    const float* pe = (const float*)d_in[2];
    const float* ne = (const float*)d_in[3];
    const float* kp = (const float*)d_in[4];
    float* out = (float*)d_out;

    float* D = (float*)d_ws;
    int useD = (ws_size >= sizeof(float) * MAX_STEPS * MAX_STEPS) ? 1 : 0;

    const int gatherBlocks = (MAX_STEPS * MAX_STEPS + 255) / 256;
    k_init_gather<<<gatherBlocks, 256, 0, stream>>>(a, s, pe, ne, D, useD, out);
    k_reg<<<REG_BLOCKS, REG_THREADS, 0, stream>>>(pe, ne, out);
    k_loss<<<1, 256, 0, stream>>>(a, s, pe, ne, kp, D, useD, out);
}